// Round 5
// baseline (1202.914 us; speedup 1.0000x reference)
//
#include <hip/hip_runtime.h>
#include <hip/hip_bf16.h>

// Problem constants (from reference): S=2048, B=4, E=512, ENC=32, H=8
// dq = ENC/H = 4, dv = E/H = 64, scaling = dq^-0.5 = 0.5
#define S_LEN 2048
#define B_SZ 4
#define E_DIM 512
#define H_NUM 8
#define DQ 4
#define DV 64

// ---------------------------------------------------------------------------
// Tiled f32 GEMM:  C[M x N] = A[M x K] @ W[N x K]^T (+ bias)
// MODE 0: plain write to C (out projection)
// MODE 1: N=576 fused QKV projection; epilogue scatters to qs/ks/vsb layouts
//   cols 0..31  -> q  (scaled 0.5) -> qs[b][h][s][dq]
//   cols 32..63 -> k               -> ks[b][h][s][dq]
//   cols 64..575-> v  (bf16)       -> vsb[b][h][s][dv]
// Tile: 64x64, K-panel 32, 256 threads, each thread 4x4 micro-tile.
// ---------------------------------------------------------------------------
template <int MODE>
__global__ __launch_bounds__(256) void gemm_bt(
    const float* __restrict__ A,
    const float* __restrict__ W1, const float* __restrict__ b1,
    const float* __restrict__ W2, const float* __restrict__ b2,
    float* __restrict__ C,
    float* __restrict__ qs, float* __restrict__ ks,
    __hip_bfloat16* __restrict__ vsb,
    int N, int K)
{
    __shared__ float As[32][64];  // A^T panel: As[k][m]
    __shared__ float Bs[32][64];  // W^T panel: Bs[k][n]

    const int m0 = blockIdx.x * 64;
    const int n0 = blockIdx.y * 64;
    const int tid = threadIdx.x;
    const int tx = tid & 15;       // col group
    const int ty = tid >> 4;       // row group

    // Which weight matrix does this block read? (block-uniform for MODE 1)
    const float* Wsel;
    int nbase;
    if (MODE == 0 || n0 < 64) { Wsel = W1; nbase = n0; }
    else                      { Wsel = W2; nbase = n0 - 64; }

    const int lrow = tid >> 3;           // 0..31
    const int lc4  = (tid & 7) << 2;     // 0,4,..,28

    float acc[4][4];
#pragma unroll
    for (int i = 0; i < 4; ++i)
#pragma unroll
        for (int j = 0; j < 4; ++j) acc[i][j] = 0.f;

    for (int kp = 0; kp < K; kp += 32) {
        // stage A tile (64x32) transposed
        float4 a0 = *(const float4*)&A[(size_t)(m0 + lrow) * K + kp + lc4];
        float4 a1 = *(const float4*)&A[(size_t)(m0 + lrow + 32) * K + kp + lc4];
        // stage W tile (64 rows x 32 k) transposed
        float4 w0 = *(const float4*)&Wsel[(size_t)(nbase + lrow) * K + kp + lc4];
        float4 w1 = *(const float4*)&Wsel[(size_t)(nbase + lrow + 32) * K + kp + lc4];
        __syncthreads();  // protect previous iteration's reads
        As[lc4 + 0][lrow] = a0.x; As[lc4 + 1][lrow] = a0.y;
        As[lc4 + 2][lrow] = a0.z; As[lc4 + 3][lrow] = a0.w;
        As[lc4 + 0][lrow + 32] = a1.x; As[lc4 + 1][lrow + 32] = a1.y;
        As[lc4 + 2][lrow + 32] = a1.z; As[lc4 + 3][lrow + 32] = a1.w;
        Bs[lc4 + 0][lrow] = w0.x; Bs[lc4 + 1][lrow] = w0.y;
        Bs[lc4 + 2][lrow] = w0.z; Bs[lc4 + 3][lrow] = w0.w;
        Bs[lc4 + 0][lrow + 32] = w1.x; Bs[lc4 + 1][lrow + 32] = w1.y;
        Bs[lc4 + 2][lrow + 32] = w1.z; Bs[lc4 + 3][lrow + 32] = w1.w;
        __syncthreads();
#pragma unroll
        for (int k = 0; k < 32; ++k) {
            float4 av = *(const float4*)&As[k][ty << 2];
            float4 bv = *(const float4*)&Bs[k][tx << 2];
            acc[0][0] = fmaf(av.x, bv.x, acc[0][0]);
            acc[0][1] = fmaf(av.x, bv.y, acc[0][1]);
            acc[0][2] = fmaf(av.x, bv.z, acc[0][2]);
            acc[0][3] = fmaf(av.x, bv.w, acc[0][3]);
            acc[1][0] = fmaf(av.y, bv.x, acc[1][0]);
            acc[1][1] = fmaf(av.y, bv.y, acc[1][1]);
            acc[1][2] = fmaf(av.y, bv.z, acc[1][2]);
            acc[1][3] = fmaf(av.y, bv.w, acc[1][3]);
            acc[2][0] = fmaf(av.z, bv.x, acc[2][0]);
            acc[2][1] = fmaf(av.z, bv.y, acc[2][1]);
            acc[2][2] = fmaf(av.z, bv.z, acc[2][2]);
            acc[2][3] = fmaf(av.z, bv.w, acc[2][3]);
            acc[3][0] = fmaf(av.w, bv.x, acc[3][0]);
            acc[3][1] = fmaf(av.w, bv.y, acc[3][1]);
            acc[3][2] = fmaf(av.w, bv.z, acc[3][2]);
            acc[3][3] = fmaf(av.w, bv.w, acc[3][3]);
        }
    }

#pragma unroll
    for (int i = 0; i < 4; ++i) {
#pragma unroll
        for (int j = 0; j < 4; ++j) {
            int m = m0 + (ty << 2) + i;
            int c = n0 + (tx << 2) + j;
            float val = acc[i][j];
            if (MODE == 0) {
                C[(size_t)m * N + c] = val + b1[c];
            } else {
                int s  = m >> 2;   // query layout [s][b][e]: row = s*B + b
                int bb = m & 3;
                if (c < 64) {
                    val += b1[c];
                    if (c < 32) {
                        // q, scaled
                        qs[((((size_t)bb * H_NUM) + (c >> 2)) * S_LEN + s) * DQ + (c & 3)] = val * 0.5f;
                    } else {
                        int j2 = c - 32;
                        ks[((((size_t)bb * H_NUM) + (j2 >> 2)) * S_LEN + s) * DQ + (j2 & 3)] = val;
                    }
                } else {
                    int j2 = c - 64;
                    val += b2[j2];
                    vsb[((((size_t)bb * H_NUM) + (j2 >> 6)) * S_LEN + s) * DV + (j2 & 63)] =
                        __float2bfloat16(val);
                }
            }
        }
    }
}

// ---------------------------------------------------------------------------
// Softmax denominator: linv[b][h][s] = 1 / sum_t exp(q[b,h,s,:] . k[b,h,t,:])
// Max-subtraction skipped deliberately: scores are Xavier-scale, |s| < ~12,
// exp() is far from f32 overflow; mathematically identical to softmax.
// One block per (bh, 256-row slab). K[b,h] (32 KB) staged in LDS.
// ---------------------------------------------------------------------------
__global__ __launch_bounds__(256) void lsum_kernel(
    const float* __restrict__ qs, const float* __restrict__ ks,
    float* __restrict__ linv)
{
    const int bh = blockIdx.x;                       // 0..31
    const int s = blockIdx.y * 256 + threadIdx.x;    // row
    __shared__ float Ksm[S_LEN][DQ];                 // 32 KB
    const float* kp = ks + (size_t)bh * S_LEN * DQ;
    for (int i = threadIdx.x; i < S_LEN; i += 256)
        *(float4*)&Ksm[i][0] = *(const float4*)&kp[(size_t)i * DQ];
    __syncthreads();

    const float4 q = *(const float4*)&qs[((size_t)bh * S_LEN + s) * DQ];
    float l = 0.f;
#pragma unroll 4
    for (int t = 0; t < S_LEN; ++t) {
        float4 kk = *(const float4*)&Ksm[t][0];
        float sc = q.x * kk.x + q.y * kk.y + q.z * kk.z + q.w * kk.w;
        l += __expf(sc);
    }
    linv[(size_t)bh * S_LEN + s] = 1.0f / l;
}

// ---------------------------------------------------------------------------
// Fused attention: per (b, 32-query-row tile) block, 512 threads (8 waves).
// Chunks over t (TT=64). For each chunk:
//   - stage K chunk for all 8 heads
//   - all threads compute p = exp(score)*linv for all heads into LDS
//     (thread owns fixed (s,t) across heads -> avg_weights accumulates in
//      registers, no atomics), writes avgw chunk coalesced
//   - PV: wave w = head w; lane = output col d; p read via broadcast b128,
//     V read from global (bf16, L2/L3 resident)
// Output ao[s][b][h*64+d] (pre-out-projection).
// ---------------------------------------------------------------------------
__global__ __launch_bounds__(512) void attn_fused(
    const float* __restrict__ qs, const float* __restrict__ ks,
    const __hip_bfloat16* __restrict__ vsb, const float* __restrict__ linv,
    float* __restrict__ aw, float* __restrict__ ao)
{
    constexpr int TQ = 32, TT = 64;
    const int b = blockIdx.x;
    const int s0 = blockIdx.y * TQ;
    const int tid = threadIdx.x;
    const int w = tid >> 6;       // wave id 0..7
    const int lane = tid & 63;

    __shared__ float Kc[H_NUM][TT][DQ];     // 8 KB
    __shared__ float pbuf[H_NUM][TQ][TT];   // 64 KB  [h][s][t]
    __shared__ float qt[H_NUM][TQ][DQ];     // 4 KB
    __shared__ float linvs[H_NUM][TQ];      // 1 KB

    if (tid < 256) {
        int h = tid >> 5, s = tid & 31;
        *(float4*)&qt[h][s][0] =
            *(const float4*)&qs[((((size_t)b * H_NUM) + h) * S_LEN + s0 + s) * DQ];
        linvs[h][s] = linv[(((size_t)b * H_NUM) + h) * S_LEN + s0 + s];
    }

    float acc[TQ];
#pragma unroll
    for (int i = 0; i < TQ; ++i) acc[i] = 0.f;

    const __hip_bfloat16* vb = vsb + (((size_t)b * H_NUM) + w) * S_LEN * DV;
    float* awrow = aw + ((size_t)b * S_LEN + s0) * S_LEN;

    for (int t0 = 0; t0 < S_LEN; t0 += TT) {
        __syncthreads();  // previous PV reads done before overwriting Kc/pbuf
        {
            int hh = tid >> 6, tt = tid & 63;
            *(float4*)&Kc[hh][tt][0] =
                *(const float4*)&ks[((((size_t)b * H_NUM) + hh) * S_LEN + t0 + tt) * DQ];
        }
        __syncthreads();

        float awacc[4] = {0.f, 0.f, 0.f, 0.f};
        for (int h = 0; h < H_NUM; ++h) {
            float4 kk = *(const float4*)&Kc[h][lane][0];
#pragma unroll
            for (int it = 0; it < 4; ++it) {
                int s = w + (it << 3);
                float4 q = *(const float4*)&qt[h][s][0];
                float sc = q.x * kk.x + q.y * kk.y + q.z * kk.z + q.w * kk.w;
                float p = __expf(sc) * linvs[h][s];
                pbuf[h][s][lane] = p;     // lane-consecutive: conflict-free
                awacc[it] += p;
            }
        }
        // avg_weights chunk write (coalesced over lane = t)
#pragma unroll
        for (int it = 0; it < 4; ++it)
            awrow[(size_t)(w + (it << 3)) * S_LEN + t0 + lane] = awacc[it] * 0.125f;

        __syncthreads();  // pbuf complete before PV

        // PV: wave w handles head w; lane = d
        for (int tg = 0; tg < TT; tg += 4) {
            float vv0 = __bfloat162float(vb[(size_t)(t0 + tg + 0) * DV + lane]);
            float vv1 = __bfloat162float(vb[(size_t)(t0 + tg + 1) * DV + lane]);
            float vv2 = __bfloat162float(vb[(size_t)(t0 + tg + 2) * DV + lane]);
            float vv3 = __bfloat162float(vb[(size_t)(t0 + tg + 3) * DV + lane]);
#pragma unroll
            for (int s = 0; s < TQ; ++s) {
                float4 p4 = *(const float4*)&pbuf[w][s][tg];  // broadcast read
                acc[s] = fmaf(p4.x, vv0, acc[s]);
                acc[s] = fmaf(p4.y, vv1, acc[s]);
                acc[s] = fmaf(p4.z, vv2, acc[s]);
                acc[s] = fmaf(p4.w, vv3, acc[s]);
            }
        }
    }

    // write pre-projection attention output: ao[(s0+s)*B + b][w*64 + lane]
#pragma unroll
    for (int s = 0; s < TQ; ++s)
        ao[((size_t)(s0 + s) * B_SZ + b) * E_DIM + (w * DV + lane)] = acc[s];
}

// ---------------------------------------------------------------------------
extern "C" void kernel_launch(void* const* d_in, const int* in_sizes, int n_in,
                              void* d_out, int out_size, void* d_ws, size_t ws_size,
                              hipStream_t stream) {
    const float* query = (const float*)d_in[0];   // [S,B,E]
    const float* ipw   = (const float*)d_in[1];   // [64,512]
    const float* ipb   = (const float*)d_in[2];   // [64]
    const float* vpw   = (const float*)d_in[3];   // [512,512]
    const float* vpb   = (const float*)d_in[4];   // [512]
    const float* opw   = (const float*)d_in[5];   // [512,512]
    const float* opb   = (const float*)d_in[6];   // [512]

    float* out_main = (float*)d_out;                       // [S,B,E] = 4,194,304 f
    float* aw       = (float*)d_out + (size_t)S_LEN * B_SZ * E_DIM;  // [B,S,S]

    // workspace carve-up (f32 slots)
    float* qs = (float*)d_ws;                              // [B][H][S][4]  1 MB
    float* ks = qs + (size_t)B_SZ * H_NUM * S_LEN * DQ;    // [B][H][S][4]  1 MB
    __hip_bfloat16* vsb = (__hip_bfloat16*)(ks + (size_t)B_SZ * H_NUM * S_LEN * DQ); // 8 MB
    float* linv = (float*)(vsb + (size_t)B_SZ * H_NUM * S_LEN * DV); // [B][H][S]
    float* ao = linv + (size_t)B_SZ * H_NUM * S_LEN;       // [S][B][E] 16 MB

    // K1: fused QKV projection (N=576)
    dim3 g1(8192 / 64, 576 / 64);
    gemm_bt<1><<<g1, 256, 0, stream>>>(query, ipw, ipb, vpw, vpb,
                                       nullptr, qs, ks, vsb, 576, E_DIM);

    // K2: softmax denominators
    lsum_kernel<<<dim3(B_SZ * H_NUM, S_LEN / 256), 256, 0, stream>>>(qs, ks, linv);

    // K3: fused attention (scores -> p -> avg_weights + PV)
    attn_fused<<<dim3(B_SZ, S_LEN / 32), 512, 0, stream>>>(qs, ks, vsb, linv, aw, ao);

    // K5: out projection (N = K = E_DIM)
    dim3 g5(8192 / 64, 512 / 64);
    gemm_bt<0><<<g5, 256, 0, stream>>>(ao, opw, opb, nullptr, nullptr,
                                       out_main, nullptr, nullptr, nullptr, E_DIM, E_DIM);
}

// Round 6
// 457.644 us; speedup vs baseline: 2.6285x; 2.6285x over previous
//
#include <hip/hip_runtime.h>
#include <hip/hip_bf16.h>

// Problem constants: S=2048, B=4, E=512, ENC=32, H=8, dq=4, dv=64, scale=0.5
#define S_LEN 2048
#define B_SZ 4
#define E_DIM 512
#define H_NUM 8
#define DQ 4
#define DV 64

typedef __attribute__((ext_vector_type(8))) short s16x8;   // 8 bf16 (4 VGPRs)
typedef __attribute__((ext_vector_type(4))) float f32x4;   // MFMA C/D

// ---------------------------------------------------------------------------
// Tiled f32 GEMM:  C[M x N] = A[M x K] @ W[N x K]^T (+ bias)   (unchanged)
// ---------------------------------------------------------------------------
template <int MODE>
__global__ __launch_bounds__(256) void gemm_bt(
    const float* __restrict__ A,
    const float* __restrict__ W1, const float* __restrict__ b1,
    const float* __restrict__ W2, const float* __restrict__ b2,
    float* __restrict__ C,
    float* __restrict__ qs, float* __restrict__ ks,
    __hip_bfloat16* __restrict__ vsb,
    int N, int K)
{
    __shared__ float As[32][64];
    __shared__ float Bs[32][64];

    const int m0 = blockIdx.x * 64;
    const int n0 = blockIdx.y * 64;
    const int tid = threadIdx.x;
    const int tx = tid & 15;
    const int ty = tid >> 4;

    const float* Wsel;
    int nbase;
    if (MODE == 0 || n0 < 64) { Wsel = W1; nbase = n0; }
    else                      { Wsel = W2; nbase = n0 - 64; }

    const int lrow = tid >> 3;
    const int lc4  = (tid & 7) << 2;

    float acc[4][4];
#pragma unroll
    for (int i = 0; i < 4; ++i)
#pragma unroll
        for (int j = 0; j < 4; ++j) acc[i][j] = 0.f;

    for (int kp = 0; kp < K; kp += 32) {
        float4 a0 = *(const float4*)&A[(size_t)(m0 + lrow) * K + kp + lc4];
        float4 a1 = *(const float4*)&A[(size_t)(m0 + lrow + 32) * K + kp + lc4];
        float4 w0 = *(const float4*)&Wsel[(size_t)(nbase + lrow) * K + kp + lc4];
        float4 w1 = *(const float4*)&Wsel[(size_t)(nbase + lrow + 32) * K + kp + lc4];
        __syncthreads();
        As[lc4 + 0][lrow] = a0.x; As[lc4 + 1][lrow] = a0.y;
        As[lc4 + 2][lrow] = a0.z; As[lc4 + 3][lrow] = a0.w;
        As[lc4 + 0][lrow + 32] = a1.x; As[lc4 + 1][lrow + 32] = a1.y;
        As[lc4 + 2][lrow + 32] = a1.z; As[lc4 + 3][lrow + 32] = a1.w;
        Bs[lc4 + 0][lrow] = w0.x; Bs[lc4 + 1][lrow] = w0.y;
        Bs[lc4 + 2][lrow] = w0.z; Bs[lc4 + 3][lrow] = w0.w;
        Bs[lc4 + 0][lrow + 32] = w1.x; Bs[lc4 + 1][lrow + 32] = w1.y;
        Bs[lc4 + 2][lrow + 32] = w1.z; Bs[lc4 + 3][lrow + 32] = w1.w;
        __syncthreads();
#pragma unroll
        for (int k = 0; k < 32; ++k) {
            float4 av = *(const float4*)&As[k][ty << 2];
            float4 bv = *(const float4*)&Bs[k][tx << 2];
            acc[0][0] = fmaf(av.x, bv.x, acc[0][0]);
            acc[0][1] = fmaf(av.x, bv.y, acc[0][1]);
            acc[0][2] = fmaf(av.x, bv.z, acc[0][2]);
            acc[0][3] = fmaf(av.x, bv.w, acc[0][3]);
            acc[1][0] = fmaf(av.y, bv.x, acc[1][0]);
            acc[1][1] = fmaf(av.y, bv.y, acc[1][1]);
            acc[1][2] = fmaf(av.y, bv.z, acc[1][2]);
            acc[1][3] = fmaf(av.y, bv.w, acc[1][3]);
            acc[2][0] = fmaf(av.z, bv.x, acc[2][0]);
            acc[2][1] = fmaf(av.z, bv.y, acc[2][1]);
            acc[2][2] = fmaf(av.z, bv.z, acc[2][2]);
            acc[2][3] = fmaf(av.z, bv.w, acc[2][3]);
            acc[3][0] = fmaf(av.w, bv.x, acc[3][0]);
            acc[3][1] = fmaf(av.w, bv.y, acc[3][1]);
            acc[3][2] = fmaf(av.w, bv.z, acc[3][2]);
            acc[3][3] = fmaf(av.w, bv.w, acc[3][3]);
        }
    }

#pragma unroll
    for (int i = 0; i < 4; ++i) {
#pragma unroll
        for (int j = 0; j < 4; ++j) {
            int m = m0 + (ty << 2) + i;
            int c = n0 + (tx << 2) + j;
            float val = acc[i][j];
            if (MODE == 0) {
                C[(size_t)m * N + c] = val + b1[c];
            } else {
                int s  = m >> 2;
                int bb = m & 3;
                if (c < 64) {
                    val += b1[c];
                    if (c < 32) {
                        qs[((((size_t)bb * H_NUM) + (c >> 2)) * S_LEN + s) * DQ + (c & 3)] = val * 0.5f;
                    } else {
                        int j2 = c - 32;
                        ks[((((size_t)bb * H_NUM) + (j2 >> 2)) * S_LEN + s) * DQ + (j2 & 3)] = val;
                    }
                } else {
                    int j2 = c - 64;
                    val += b2[j2];
                    vsb[((((size_t)bb * H_NUM) + (j2 >> 6)) * S_LEN + s) * DV + (j2 & 63)] =
                        __float2bfloat16(val);
                }
            }
        }
    }
}

// ---------------------------------------------------------------------------
// Softmax denominator (unchanged). No-max softmax is exact here: Xavier-scale
// scores |s| < ~12, far from f32 exp overflow.
// ---------------------------------------------------------------------------
__global__ __launch_bounds__(256) void lsum_kernel(
    const float* __restrict__ qs, const float* __restrict__ ks,
    float* __restrict__ linv)
{
    const int bh = blockIdx.x;
    const int s = blockIdx.y * 256 + threadIdx.x;
    __shared__ float Ksm[S_LEN][DQ];
    const float* kp = ks + (size_t)bh * S_LEN * DQ;
    for (int i = threadIdx.x; i < S_LEN; i += 256)
        *(float4*)&Ksm[i][0] = *(const float4*)&kp[(size_t)i * DQ];
    __syncthreads();

    const float4 q = *(const float4*)&qs[((size_t)bh * S_LEN + s) * DQ];
    float l = 0.f;
#pragma unroll 4
    for (int t = 0; t < S_LEN; ++t) {
        float4 kk = *(const float4*)&Ksm[t][0];
        float sc = q.x * kk.x + q.y * kk.y + q.z * kk.z + q.w * kk.w;
        l += __expf(sc);
    }
    linv[(size_t)bh * S_LEN + s] = 1.0f / l;
}

// ---------------------------------------------------------------------------
// Fused attention with MFMA PV.
// Block = (b, 32-query tile), 512 threads / 8 waves, chunk TT=64 over t.
// Per chunk:
//   stage: Kc[h][t][4] f32 (wave w -> head w); vt[h][d][t] bf16 transposed
//          (wave w reads V rows coalesced, scalar-writes its head's V^T)
//   score: thread (w,lane): s in {w,w+8,w+16,w+24}, t=lane; all 8 heads;
//          p=exp(sc)*linv -> pb[h][s][t] bf16; aw accumulated in f32 regs
//   PV:    wave w = head w: acc[2][4] (M=32,N=64) via mfma_f32_16x16x32_bf16,
//          A-frag from pb[w], B-frag from vt[w] (both rows padded to 72 bf16
//          = 144B stride -> frag reads at the conflict floor)
// MFMA frag layout (16x16x32): A[row=l&15][k=(l>>4)*8+j], B[k][col=l&15],
// C/D: col=l&15, row=(l>>4)*4+reg  [per m89 verified mapping].
// ---------------------------------------------------------------------------
__global__ __launch_bounds__(512) void attn_fused(
    const float* __restrict__ qs, const float* __restrict__ ks,
    const unsigned short* __restrict__ vsb, const float* __restrict__ linv,
    float* __restrict__ aw, float* __restrict__ ao)
{
    constexpr int TQ = 32, TT = 64, PP = 72;   // PP: padded row (bf16 elems)
    const int b = blockIdx.x;
    const int s0 = blockIdx.y * TQ;
    const int tid = threadIdx.x;
    const int w = tid >> 6;
    const int lane = tid & 63;

    __shared__ float Kc[H_NUM][TT][DQ];                       //  8 KB
    __shared__ float qt[H_NUM][TQ][DQ];                       //  4 KB
    __shared__ float linvs[H_NUM][TQ];                        //  1 KB
    __shared__ __align__(16) unsigned short pb[H_NUM][TQ][PP]; // 36 KB bf16 P
    __shared__ __align__(16) unsigned short vt[H_NUM][DV][PP]; // 72 KB bf16 V^T

    if (tid < 256) {
        int h = tid >> 5, s = tid & 31;
        *(float4*)&qt[h][s][0] =
            *(const float4*)&qs[((((size_t)b * H_NUM) + h) * S_LEN + s0 + s) * DQ];
        linvs[h][s] = linv[(((size_t)b * H_NUM) + h) * S_LEN + s0 + s];
    }

    f32x4 acc[2][4];
#pragma unroll
    for (int m = 0; m < 2; ++m)
#pragma unroll
        for (int n = 0; n < 4; ++n) acc[m][n] = (f32x4){0.f, 0.f, 0.f, 0.f};

    const unsigned short* vb = vsb + (((size_t)b * H_NUM) + w) * S_LEN * DV;
    const float* krow = ks + (((size_t)b * H_NUM) + w) * S_LEN * DQ;
    float* awrow = aw + ((size_t)b * S_LEN + s0) * S_LEN;

    const int fr = lane & 15;           // frag row/col index
    const int fk = (lane >> 4) << 3;    // frag k-offset (0,8,16,24)

    for (int t0 = 0; t0 < S_LEN; t0 += TT) {
        __syncthreads();   // prev PV reads done before restaging

        // stage K chunk: wave w -> head w, lane -> t  (f32, for score phase)
        *(float4*)&Kc[w][lane][0] = *(const float4*)&krow[(size_t)(t0 + lane) * DQ];

        // stage V^T chunk: wave w reads its head's V rows coalesced (128B/lane),
        // scalar-writes transposed. Write pattern per (g,j): 64 lanes write
        // 128B contiguous -> 2 lanes/bank (free).
        {
            const unsigned short* vrow = vb + (size_t)(t0 + lane) * DV;
#pragma unroll
            for (int g = 0; g < 8; ++g) {
                s16x8 vv = *(const s16x8*)(vrow + (g << 3));
#pragma unroll
                for (int j = 0; j < 8; ++j)
                    vt[w][(g << 3) + j][lane] = (unsigned short)vv[j];
            }
        }
        __syncthreads();

        // score phase: all heads, thread owns (s = w+it*8, t = lane)
        float awacc[4] = {0.f, 0.f, 0.f, 0.f};
        for (int h = 0; h < H_NUM; ++h) {
            float4 kk = *(const float4*)&Kc[h][lane][0];
#pragma unroll
            for (int it = 0; it < 4; ++it) {
                int s = w + (it << 3);
                float4 q = *(const float4*)&qt[h][s][0];
                float sc = q.x * kk.x + q.y * kk.y + q.z * kk.z + q.w * kk.w;
                float p = __expf(sc) * linvs[h][s];
                __hip_bfloat16 hb = __float2bfloat16(p);
                pb[h][s][lane] = *(unsigned short*)&hb;
                awacc[it] += p;   // aw from f32 p (full precision)
            }
        }
#pragma unroll
        for (int it = 0; it < 4; ++it)
            awrow[(size_t)(w + (it << 3)) * S_LEN + t0 + lane] = awacc[it] * 0.125f;

        __syncthreads();   // pb + vt complete before PV

        // PV MFMA: wave w, head w. M=32 (2 mb) x N=64 (4 nb), K=TT=64 (2 kb)
#pragma unroll
        for (int kb = 0; kb < 2; ++kb) {
            s16x8 a0 = *(const s16x8*)&pb[w][fr][(kb << 5) + fk];
            s16x8 a1 = *(const s16x8*)&pb[w][16 + fr][(kb << 5) + fk];
#pragma unroll
            for (int n = 0; n < 4; ++n) {
                s16x8 bb = *(const s16x8*)&vt[w][(n << 4) + fr][(kb << 5) + fk];
                acc[0][n] = __builtin_amdgcn_mfma_f32_16x16x32_bf16(a0, bb, acc[0][n], 0, 0, 0);
                acc[1][n] = __builtin_amdgcn_mfma_f32_16x16x32_bf16(a1, bb, acc[1][n], 0, 0, 0);
            }
        }
    }

    // epilogue: C/D layout -> s = m*16 + (lane>>4)*4 + j, d = n*16 + (lane&15)
#pragma unroll
    for (int m = 0; m < 2; ++m)
#pragma unroll
        for (int n = 0; n < 4; ++n)
#pragma unroll
            for (int j = 0; j < 4; ++j) {
                int s = (m << 4) + ((lane >> 4) << 2) + j;
                int d = (n << 4) + (lane & 15);
                ao[((size_t)(s0 + s) * B_SZ + b) * E_DIM + (w * DV + d)] = acc[m][n][j];
            }
}

// ---------------------------------------------------------------------------
extern "C" void kernel_launch(void* const* d_in, const int* in_sizes, int n_in,
                              void* d_out, int out_size, void* d_ws, size_t ws_size,
                              hipStream_t stream) {
    const float* query = (const float*)d_in[0];
    const float* ipw   = (const float*)d_in[1];
    const float* ipb   = (const float*)d_in[2];
    const float* vpw   = (const float*)d_in[3];
    const float* vpb   = (const float*)d_in[4];
    const float* opw   = (const float*)d_in[5];
    const float* opb   = (const float*)d_in[6];

    float* out_main = (float*)d_out;
    float* aw       = (float*)d_out + (size_t)S_LEN * B_SZ * E_DIM;

    float* qs = (float*)d_ws;
    float* ks = qs + (size_t)B_SZ * H_NUM * S_LEN * DQ;
    __hip_bfloat16* vsb = (__hip_bfloat16*)(ks + (size_t)B_SZ * H_NUM * S_LEN * DQ);
    float* linv = (float*)(vsb + (size_t)B_SZ * H_NUM * S_LEN * DV);
    float* ao = linv + (size_t)B_SZ * H_NUM * S_LEN;

    // K1: fused QKV projection (N=576)
    dim3 g1(8192 / 64, 576 / 64);
    gemm_bt<1><<<g1, 256, 0, stream>>>(query, ipw, ipb, vpw, vpb,
                                       nullptr, qs, ks, vsb, 576, E_DIM);

    // K2: softmax denominators
    lsum_kernel<<<dim3(B_SZ * H_NUM, S_LEN / 256), 256, 0, stream>>>(qs, ks, linv);

    // K3: fused attention (scores -> p -> avg_weights + MFMA PV)
    attn_fused<<<dim3(B_SZ, S_LEN / 32), 512, 0, stream>>>(
        qs, ks, (const unsigned short*)vsb, linv, aw, ao);

    // K5: out projection (N = K = E_DIM)
    dim3 g5(8192 / 64, 512 / 64);
    gemm_bt<0><<<g5, 256, 0, stream>>>(ao, opw, opb, nullptr, nullptr,
                                       out_main, nullptr, nullptr, nullptr, E_DIM, E_DIM);
}

// Round 7
// 328.483 us; speedup vs baseline: 3.6620x; 1.3932x over previous
//
#include <hip/hip_runtime.h>
#include <hip/hip_bf16.h>

// Problem constants: S=2048, B=4, E=512, ENC=32, H=8, dq=4, dv=64, scale=0.5
#define S_LEN 2048
#define B_SZ 4
#define E_DIM 512
#define H_NUM 8
#define DQ 4
#define DV 64

typedef __attribute__((ext_vector_type(8))) short s16x8;   // 8 bf16
typedef __attribute__((ext_vector_type(4))) float f32x4;   // MFMA C/D
typedef unsigned short u16;

__device__ __forceinline__ u16 f2b(float x) {
    __hip_bfloat16 h = __float2bfloat16(x);
    return *(u16*)&h;
}

// ---------------------------------------------------------------------------
// K0: cast query + 3 weight matrices to bf16 (grid-stride, 8 elems/thread)
// ---------------------------------------------------------------------------
__global__ __launch_bounds__(256) void cast_bf16(
    const float* __restrict__ q,  u16* __restrict__ qb,
    const float* __restrict__ w1, u16* __restrict__ w1b,
    const float* __restrict__ w2, u16* __restrict__ w2b,
    const float* __restrict__ w3, u16* __restrict__ w3b)
{
    const int NQ = S_LEN * B_SZ * E_DIM / 8;   // 524288
    const int N1 = 64 * E_DIM / 8;             // 4096
    const int N2 = E_DIM * E_DIM / 8;          // 32768
    const int total = NQ + N1 + 2 * N2;
    for (int g = blockIdx.x * 256 + threadIdx.x; g < total; g += gridDim.x * 256) {
        const float* src; u16* dst; int off;
        if (g < NQ)                { src = q;  dst = qb;  off = g; }
        else if (g < NQ + N1)      { src = w1; dst = w1b; off = g - NQ; }
        else if (g < NQ + N1 + N2) { src = w2; dst = w2b; off = g - NQ - N1; }
        else                       { src = w3; dst = w3b; off = g - NQ - N1 - N2; }
        float4 a = ((const float4*)src)[(size_t)off * 2];
        float4 b = ((const float4*)src)[(size_t)off * 2 + 1];
        s16x8 o;
        o[0] = f2b(a.x); o[1] = f2b(a.y); o[2] = f2b(a.z); o[3] = f2b(a.w);
        o[4] = f2b(b.x); o[5] = f2b(b.y); o[6] = f2b(b.z); o[7] = f2b(b.w);
        ((s16x8*)dst)[off] = o;
    }
}

// ---------------------------------------------------------------------------
// bf16 MFMA GEMM: C[M x N] = A[M x K] @ W[N x K]^T (+ bias, f32)
// BM=128, BN=64, BK=64; 256 thr = 4 waves (2M x 2N); wave tile 64x32.
// LDS rows padded to 72 bf16 (144B = 36 words): frag reads (16 lanes, rows
// r..r+15, stride 36 words -> bank 4(r+p)%32) are 2-way = free.
// MODE 0: plain C + b1. MODE 1: QKV epilogue scatter (q*0.5 / k f32, v bf16).
// MFMA 16x16x32_bf16 operand maps (HW-verified in R6 PV):
//   A elem j of lane l = A[l&15][(l>>4)*8+j]   (read As[row][k] contiguous k)
//   B elem j of lane l = B[(l>>4)*8+j][l&15]   (read Bs[col][k] contiguous k)
//   C/D: col=l&15, row=(l>>4)*4+reg
// ---------------------------------------------------------------------------
template <int MODE>
__global__ __launch_bounds__(256) void gemm_mfma(
    const u16* __restrict__ Abf,
    const u16* __restrict__ W1, const float* __restrict__ b1,
    const u16* __restrict__ W2, const float* __restrict__ b2,
    float* __restrict__ C,
    float* __restrict__ qs, float* __restrict__ ks,
    u16* __restrict__ vsb,
    int N, int K)
{
    constexpr int PP = 72;
    __shared__ __align__(16) u16 As[128][PP];  // 18 KB
    __shared__ __align__(16) u16 Bs[64][PP];   //  9 KB

    const int m0 = blockIdx.x * 128;
    const int n0 = blockIdx.y * 64;
    const int tid = threadIdx.x;
    const int w = tid >> 6, lane = tid & 63;
    const int wm = w >> 1, wn = w & 1;       // wave tile: rows wm*64, cols wn*32
    const int fr = lane & 15;
    const int fk = (lane >> 4) << 3;

    const u16* Wsel; int nbase;
    if (MODE == 0 || n0 < 64) { Wsel = W1; nbase = n0; }
    else                      { Wsel = W2; nbase = n0 - 64; }

    // staging maps: A: thread -> (row=tid>>1, 32-elem half); B: (row=tid>>2, 16-elem quarter)
    const int ar = tid >> 1, ah = (tid & 1) << 5;
    const int br = tid >> 2, bq = (tid & 3) << 4;

    f32x4 acc[4][2];
#pragma unroll
    for (int mt = 0; mt < 4; ++mt)
#pragma unroll
        for (int nt = 0; nt < 2; ++nt) acc[mt][nt] = (f32x4){0.f, 0.f, 0.f, 0.f};

    for (int kp = 0; kp < K; kp += 64) {
        const s16x8* ap = (const s16x8*)&Abf[(size_t)(m0 + ar) * K + kp + ah];
        s16x8 a0 = ap[0], a1 = ap[1], a2 = ap[2], a3 = ap[3];
        const s16x8* bp = (const s16x8*)&Wsel[(size_t)(nbase + br) * K + kp + bq];
        s16x8 b0 = bp[0], b1v = bp[1];
        __syncthreads();   // previous iteration's frag reads complete
        *(s16x8*)&As[ar][ah + 0]  = a0;
        *(s16x8*)&As[ar][ah + 8]  = a1;
        *(s16x8*)&As[ar][ah + 16] = a2;
        *(s16x8*)&As[ar][ah + 24] = a3;
        *(s16x8*)&Bs[br][bq + 0]  = b0;
        *(s16x8*)&Bs[br][bq + 8]  = b1v;
        __syncthreads();

#pragma unroll
        for (int kb = 0; kb < 2; ++kb) {
            s16x8 bf0 = *(const s16x8*)&Bs[wn * 32 + fr][(kb << 5) + fk];
            s16x8 bf1 = *(const s16x8*)&Bs[wn * 32 + 16 + fr][(kb << 5) + fk];
#pragma unroll
            for (int mt = 0; mt < 4; ++mt) {
                s16x8 af = *(const s16x8*)&As[wm * 64 + mt * 16 + fr][(kb << 5) + fk];
                acc[mt][0] = __builtin_amdgcn_mfma_f32_16x16x32_bf16(af, bf0, acc[mt][0], 0, 0, 0);
                acc[mt][1] = __builtin_amdgcn_mfma_f32_16x16x32_bf16(af, bf1, acc[mt][1], 0, 0, 0);
            }
        }
    }

#pragma unroll
    for (int mt = 0; mt < 4; ++mt)
#pragma unroll
        for (int nt = 0; nt < 2; ++nt)
#pragma unroll
            for (int j = 0; j < 4; ++j) {
                int m = m0 + wm * 64 + mt * 16 + ((lane >> 4) << 2) + j;
                int c = n0 + wn * 32 + nt * 16 + fr;
                float val = acc[mt][nt][j];
                if (MODE == 0) {
                    C[(size_t)m * N + c] = val + b1[c];
                } else {
                    int s  = m >> 2;        // A row = s*B + b
                    int bb = m & 3;
                    if (c < 64) {
                        val += b1[c];
                        if (c < 32) {
                            qs[((((size_t)bb * H_NUM) + (c >> 2)) * S_LEN + s) * DQ + (c & 3)] = val * 0.5f;
                        } else {
                            int j2 = c - 32;
                            ks[((((size_t)bb * H_NUM) + (j2 >> 2)) * S_LEN + s) * DQ + (j2 & 3)] = val;
                        }
                    } else {
                        int j2 = c - 64;
                        val += b2[j2];
                        vsb[((((size_t)bb * H_NUM) + (j2 >> 6)) * S_LEN + s) * DV + (j2 & 63)] = f2b(val);
                    }
                }
            }
}

// ---------------------------------------------------------------------------
// K2: softmax denominators, 4-way t-split for occupancy (4 waves/block,
// grid 32 x 32 -> 16 waves/CU vs old 1 wave/SIMD). No-max softmax is exact:
// Xavier-scale scores |s| < ~12, far from f32 exp overflow.
// ---------------------------------------------------------------------------
__global__ __launch_bounds__(256) void lsum_kernel(
    const float* __restrict__ qs, const float* __restrict__ ks,
    float* __restrict__ linv)
{
    const int bh = blockIdx.x;                 // 0..31
    const int s0 = blockIdx.y * 64;
    const int sl = threadIdx.x >> 2;           // 0..63 row
    const int tq = threadIdx.x & 3;            // t-quarter
    __shared__ float Ksm[S_LEN][DQ];           // 32 KB
    __shared__ float part[64][4];
    const float* kp = ks + (size_t)bh * S_LEN * DQ;
    for (int i = threadIdx.x; i < S_LEN; i += 256)
        *(float4*)&Ksm[i][0] = *(const float4*)&kp[(size_t)i * DQ];
    __syncthreads();

    const float4 q = *(const float4*)&qs[((size_t)bh * S_LEN + s0 + sl) * DQ];
    float l = 0.f;
    const int t0 = tq * (S_LEN / 4);
#pragma unroll 4
    for (int t = t0; t < t0 + S_LEN / 4; ++t) {
        float4 kk = *(const float4*)&Ksm[t][0];
        float sc = q.x * kk.x + q.y * kk.y + q.z * kk.z + q.w * kk.w;
        l += __expf(sc);
    }
    part[sl][tq] = l;
    __syncthreads();
    if (threadIdx.x < 64) {
        float tsum = part[threadIdx.x][0] + part[threadIdx.x][1] +
                     part[threadIdx.x][2] + part[threadIdx.x][3];
        linv[(size_t)bh * S_LEN + s0 + threadIdx.x] = 1.0f / tsum;
    }
}

// ---------------------------------------------------------------------------
// K3: fused attention with MFMA PV (unchanged from R6 except bf16 ao output).
// ---------------------------------------------------------------------------
__global__ __launch_bounds__(512) void attn_fused(
    const float* __restrict__ qs, const float* __restrict__ ks,
    const u16* __restrict__ vsb, const float* __restrict__ linv,
    float* __restrict__ aw, u16* __restrict__ ao)
{
    constexpr int TQ = 32, TT = 64, PP = 72;
    const int b = blockIdx.x;
    const int s0 = blockIdx.y * TQ;
    const int tid = threadIdx.x;
    const int w = tid >> 6;
    const int lane = tid & 63;

    __shared__ float Kc[H_NUM][TT][DQ];
    __shared__ float qt[H_NUM][TQ][DQ];
    __shared__ float linvs[H_NUM][TQ];
    __shared__ __align__(16) u16 pb[H_NUM][TQ][PP];
    __shared__ __align__(16) u16 vt[H_NUM][DV][PP];

    if (tid < 256) {
        int h = tid >> 5, s = tid & 31;
        *(float4*)&qt[h][s][0] =
            *(const float4*)&qs[((((size_t)b * H_NUM) + h) * S_LEN + s0 + s) * DQ];
        linvs[h][s] = linv[(((size_t)b * H_NUM) + h) * S_LEN + s0 + s];
    }

    f32x4 acc[2][4];
#pragma unroll
    for (int m = 0; m < 2; ++m)
#pragma unroll
        for (int n = 0; n < 4; ++n) acc[m][n] = (f32x4){0.f, 0.f, 0.f, 0.f};

    const u16* vb = vsb + (((size_t)b * H_NUM) + w) * S_LEN * DV;
    const float* krow = ks + (((size_t)b * H_NUM) + w) * S_LEN * DQ;
    float* awrow = aw + ((size_t)b * S_LEN + s0) * S_LEN;

    const int fr = lane & 15;
    const int fk = (lane >> 4) << 3;

    for (int t0 = 0; t0 < S_LEN; t0 += TT) {
        __syncthreads();

        *(float4*)&Kc[w][lane][0] = *(const float4*)&krow[(size_t)(t0 + lane) * DQ];
        {
            const u16* vrow = vb + (size_t)(t0 + lane) * DV;
#pragma unroll
            for (int g = 0; g < 8; ++g) {
                s16x8 vv = *(const s16x8*)(vrow + (g << 3));
#pragma unroll
                for (int j = 0; j < 8; ++j)
                    vt[w][(g << 3) + j][lane] = (u16)vv[j];
            }
        }
        __syncthreads();

        float awacc[4] = {0.f, 0.f, 0.f, 0.f};
        for (int h = 0; h < H_NUM; ++h) {
            float4 kk = *(const float4*)&Kc[h][lane][0];
#pragma unroll
            for (int it = 0; it < 4; ++it) {
                int s = w + (it << 3);
                float4 q = *(const float4*)&qt[h][s][0];
                float sc = q.x * kk.x + q.y * kk.y + q.z * kk.z + q.w * kk.w;
                float p = __expf(sc) * linvs[h][s];
                pb[h][s][lane] = f2b(p);
                awacc[it] += p;
            }
        }
#pragma unroll
        for (int it = 0; it < 4; ++it)
            awrow[(size_t)(w + (it << 3)) * S_LEN + t0 + lane] = awacc[it] * 0.125f;

        __syncthreads();

#pragma unroll
        for (int kb = 0; kb < 2; ++kb) {
            s16x8 a0 = *(const s16x8*)&pb[w][fr][(kb << 5) + fk];
            s16x8 a1 = *(const s16x8*)&pb[w][16 + fr][(kb << 5) + fk];
#pragma unroll
            for (int n = 0; n < 4; ++n) {
                s16x8 bb = *(const s16x8*)&vt[w][(n << 4) + fr][(kb << 5) + fk];
                acc[0][n] = __builtin_amdgcn_mfma_f32_16x16x32_bf16(a0, bb, acc[0][n], 0, 0, 0);
                acc[1][n] = __builtin_amdgcn_mfma_f32_16x16x32_bf16(a1, bb, acc[1][n], 0, 0, 0);
            }
        }
    }

    // epilogue: bf16 ao (feeds out-proj MFMA A directly)
#pragma unroll
    for (int m = 0; m < 2; ++m)
#pragma unroll
        for (int n = 0; n < 4; ++n)
#pragma unroll
            for (int j = 0; j < 4; ++j) {
                int s = (m << 4) + ((lane >> 4) << 2) + j;
                int d = (n << 4) + (lane & 15);
                ao[((size_t)(s0 + s) * B_SZ + b) * E_DIM + (w * DV + d)] =
                    f2b(acc[m][n][j]);
            }
}

// ---------------------------------------------------------------------------
extern "C" void kernel_launch(void* const* d_in, const int* in_sizes, int n_in,
                              void* d_out, int out_size, void* d_ws, size_t ws_size,
                              hipStream_t stream) {
    const float* query = (const float*)d_in[0];
    const float* ipw   = (const float*)d_in[1];
    const float* ipb   = (const float*)d_in[2];
    const float* vpw   = (const float*)d_in[3];
    const float* vpb   = (const float*)d_in[4];
    const float* opw   = (const float*)d_in[5];
    const float* opb   = (const float*)d_in[6];

    float* out_main = (float*)d_out;
    float* aw       = (float*)d_out + (size_t)S_LEN * B_SZ * E_DIM;

    // workspace carve-up
    const size_t NQKV = (size_t)B_SZ * H_NUM * S_LEN;   // 65536
    float* qs   = (float*)d_ws;                          // 262144 f  (1 MB)
    float* ks   = qs + NQKV * DQ;                        // 262144 f  (1 MB)
    float* linv = ks + NQKV * DQ;                        // 65536 f
    u16* vsb    = (u16*)(linv + NQKV);                   // 4.19M u16 (8 MB)
    u16* qbf    = vsb + (size_t)S_LEN * B_SZ * E_DIM;    // 4.19M u16 (8 MB)
    u16* aobf   = qbf;   // alias: qbf dead after K1, aobf written in K3
    u16* ipwbf  = qbf + (size_t)S_LEN * B_SZ * E_DIM;    // 32768
    u16* vpwbf  = ipwbf + 64 * E_DIM;                    // 262144
    u16* opwbf  = vpwbf + (size_t)E_DIM * E_DIM;         // 262144

    // K0: cast query + weights to bf16
    cast_bf16<<<1024, 256, 0, stream>>>(query, qbf, ipw, ipwbf, vpw, vpwbf, opw, opwbf);

    // K1: fused QKV projection (MFMA, N=576)
    dim3 g1(8192 / 128, 576 / 64);
    gemm_mfma<1><<<g1, 256, 0, stream>>>(qbf, ipwbf, ipb, vpwbf, vpb,
                                         nullptr, qs, ks, vsb, 576, E_DIM);

    // K2: softmax denominators (4-way t-split)
    lsum_kernel<<<dim3(B_SZ * H_NUM, S_LEN / 64), 256, 0, stream>>>(qs, ks, linv);

    // K3: fused attention (scores -> p -> avg_weights + MFMA PV)
    attn_fused<<<dim3(B_SZ, S_LEN / 32), 512, 0, stream>>>(qs, ks, vsb, linv, aw, aobf);

    // K4: out projection (MFMA, N = K = E_DIM)
    dim3 g4(8192 / 128, 512 / 64);
    gemm_mfma<0><<<g4, 256, 0, stream>>>(aobf, opwbf, opb, nullptr, nullptr,
                                         out_main, nullptr, nullptr, nullptr, E_DIM, E_DIM);
}